// Round 1
// baseline (1136.666 us; speedup 1.0000x reference)
//
#include <hip/hip_runtime.h>
#include <hip/hip_bf16.h>

// Problem constants
constexpr int Bc = 16, Sc = 512, Hc = 256, Vc = 8000, NHc = 4, HDc = 64;
constexpr int FFc = 512, Mc = 64;
constexpr int ROWS = Bc * Sc;      // 8192
constexpr int CH = 4 * Hc;         // 1024

typedef __attribute__((ext_vector_type(4))) float f32x4v;
typedef __attribute__((ext_vector_type(8))) short short8v;

// ---------------- embed + pos ----------------
__global__ __launch_bounds__(256) void k_embed(const int* __restrict__ ids,
                                               const float* __restrict__ emb,
                                               const float* __restrict__ pos,
                                               float* __restrict__ x) {
    const int r = blockIdx.x;          // 0..8191
    const int h = threadIdx.x;         // 0..255
    const int s = r & (Sc - 1);
    const int id = ids[r];
    x[(size_t)r * Hc + h] = emb[(size_t)id * Hc + h] + pos[(size_t)s * Hc + h];
}

// ---------------- generic fp32 GEMM: C = A[M,K] @ B[N,K]^T + bias, optional GELU ----------------
template <int EPI>
__global__ __launch_bounds__(256) void k_gemm_nt(const float* __restrict__ A,
                                                 const float* __restrict__ Bm,
                                                 const float* __restrict__ bias,
                                                 float* __restrict__ C,
                                                 int M, int N, int K) {
    __shared__ float As[16][68];
    __shared__ float Bs[16][68];
    const int t = threadIdx.x;
    const int tx = t & 15, ty = t >> 4;
    const int tm = blockIdx.x * 64, tn = blockIdx.y * 64;
    float acc[4][4] = {};
    for (int kt = 0; kt < K; kt += 16) {
#pragma unroll
        for (int q = 0; q < 4; ++q) {
            int idx = t + q * 256;
            int r = idx >> 4, kk = idx & 15;
            As[kk][r] = A[(size_t)(tm + r) * K + (kt + kk)];
            Bs[kk][r] = Bm[(size_t)(tn + r) * K + (kt + kk)];
        }
        __syncthreads();
#pragma unroll
        for (int kk = 0; kk < 16; ++kk) {
            const float4 a4 = *(const float4*)&As[kk][ty * 4];
            const float4 b4 = *(const float4*)&Bs[kk][tx * 4];
            const float ar[4] = {a4.x, a4.y, a4.z, a4.w};
            const float br[4] = {b4.x, b4.y, b4.z, b4.w};
#pragma unroll
            for (int i = 0; i < 4; ++i)
#pragma unroll
                for (int j = 0; j < 4; ++j)
                    acc[i][j] = fmaf(ar[i], br[j], acc[i][j]);
        }
        __syncthreads();
    }
#pragma unroll
    for (int i = 0; i < 4; ++i) {
        const size_t r = tm + ty * 4 + i;
#pragma unroll
        for (int j = 0; j < 4; ++j) {
            const int c = tn + tx * 4 + j;
            float v = acc[i][j] + bias[c];
            if (EPI == 1) v = 0.5f * v * (1.0f + erff(v / 1.41421356237309515f));
            C[r * N + c] = v;
        }
    }
}

// ---------------- attention scores: att[z,q,k] = (q . k)/8 ----------------
__global__ __launch_bounds__(256) void k_scores(const float* __restrict__ qkv,
                                                float* __restrict__ att) {
    const int z = blockIdx.z;            // b*NH + h
    const int b = z >> 2, h = z & 3;
    const float* qb = qkv + (size_t)b * Sc * (3 * Hc) + h * HDc;
    const float* kb = qb + Hc;
    __shared__ float Qs[64][68];
    __shared__ float Ks[64][68];
    const int tm = blockIdx.x * 64, tn = blockIdx.y * 64;
    const int t = threadIdx.x;
#pragma unroll
    for (int q = 0; q < 16; ++q) {
        int idx = t + q * 256;
        int r = idx >> 6, c = idx & 63;
        Qs[c][r] = qb[(size_t)(tm + r) * (3 * Hc) + c];
        Ks[c][r] = kb[(size_t)(tn + r) * (3 * Hc) + c];
    }
    __syncthreads();
    const int tx = t & 15, ty = t >> 4;
    float acc[4][4] = {};
#pragma unroll 4
    for (int kk = 0; kk < 64; ++kk) {
        const float4 a4 = *(const float4*)&Qs[kk][ty * 4];
        const float4 b4 = *(const float4*)&Ks[kk][tx * 4];
        const float ar[4] = {a4.x, a4.y, a4.z, a4.w};
        const float br[4] = {b4.x, b4.y, b4.z, b4.w};
#pragma unroll
        for (int i = 0; i < 4; ++i)
#pragma unroll
            for (int j = 0; j < 4; ++j)
                acc[i][j] = fmaf(ar[i], br[j], acc[i][j]);
    }
    float* ob = att + (size_t)z * Sc * Sc;
#pragma unroll
    for (int i = 0; i < 4; ++i)
#pragma unroll
        for (int j = 0; j < 4; ++j)
            ob[(size_t)(tm + ty * 4 + i) * Sc + (tn + tx * 4 + j)] = acc[i][j] * 0.125f;
}

// ---------------- softmax over 512-wide rows ----------------
__global__ __launch_bounds__(256) void k_softmax(float* __restrict__ att) {
    float* p = att + (size_t)blockIdx.x * Sc;
    const int t = threadIdx.x;
    float v0 = p[t], v1 = p[t + 256];
    __shared__ float red[256];
    red[t] = fmaxf(v0, v1);
    __syncthreads();
    for (int s = 128; s > 0; s >>= 1) { if (t < s) red[t] = fmaxf(red[t], red[t + s]); __syncthreads(); }
    const float mx = red[0];
    __syncthreads();
    const float e0 = expf(v0 - mx), e1 = expf(v1 - mx);
    red[t] = e0 + e1;
    __syncthreads();
    for (int s = 128; s > 0; s >>= 1) { if (t < s) red[t] += red[t + s]; __syncthreads(); }
    const float sum = red[0];
    p[t] = e0 / sum;
    p[t + 256] = e1 / sum;
}

// ---------------- o = att @ v ----------------
__global__ __launch_bounds__(256) void k_av(const float* __restrict__ att,
                                            const float* __restrict__ qkv,
                                            float* __restrict__ O) {
    const int z = blockIdx.y;
    const int b = z >> 2, h = z & 3;
    const float* ab = att + (size_t)z * Sc * Sc;
    const float* vb = qkv + (size_t)b * Sc * (3 * Hc) + 2 * Hc + h * HDc;
    const int tm = blockIdx.x * 64;
    __shared__ float As[32][68];
    __shared__ float Vs[32][68];
    const int t = threadIdx.x, tx = t & 15, ty = t >> 4;
    float acc[4][4] = {};
    for (int kt = 0; kt < Sc; kt += 32) {
#pragma unroll
        for (int q = 0; q < 8; ++q) {
            int idx = t + q * 256;
            int r = idx >> 5, kk = idx & 31;
            As[kk][r] = ab[(size_t)(tm + r) * Sc + kt + kk];
            int kv = idx >> 6, c = idx & 63;
            Vs[kv][c] = vb[(size_t)(kt + kv) * (3 * Hc) + c];
        }
        __syncthreads();
#pragma unroll 4
        for (int kk = 0; kk < 32; ++kk) {
            const float4 a4 = *(const float4*)&As[kk][ty * 4];
            const float4 b4 = *(const float4*)&Vs[kk][tx * 4];
            const float ar[4] = {a4.x, a4.y, a4.z, a4.w};
            const float br[4] = {b4.x, b4.y, b4.z, b4.w};
#pragma unroll
            for (int i = 0; i < 4; ++i)
#pragma unroll
                for (int j = 0; j < 4; ++j)
                    acc[i][j] = fmaf(ar[i], br[j], acc[i][j]);
        }
        __syncthreads();
    }
#pragma unroll
    for (int i = 0; i < 4; ++i)
#pragma unroll
        for (int j = 0; j < 4; ++j)
            O[(size_t)(b * Sc + tm + ty * 4 + i) * Hc + h * HDc + tx * 4 + j] = acc[i][j];
}

// ---------------- x = LayerNorm(x + res) * g + b ----------------
__global__ __launch_bounds__(256) void k_add_ln(float* __restrict__ x,
                                                const float* __restrict__ res,
                                                const float* __restrict__ g,
                                                const float* __restrict__ b) {
    const size_t row = blockIdx.x;
    const int t = threadIdx.x;
    float v = x[row * Hc + t] + res[row * Hc + t];
    __shared__ float red[256];
    red[t] = v;
    __syncthreads();
    for (int s = 128; s > 0; s >>= 1) { if (t < s) red[t] += red[t + s]; __syncthreads(); }
    const float mean = red[0] * (1.0f / 256.0f);
    __syncthreads();
    const float d = v - mean;
    red[t] = d * d;
    __syncthreads();
    for (int s = 128; s > 0; s >>= 1) { if (t < s) red[t] += red[t + s]; __syncthreads(); }
    const float var = red[0] * (1.0f / 256.0f);
    x[row * Hc + t] = d / sqrtf(var + 1e-5f) * g[t] + b[t];
}

// ---------------- LIF scan; writes 0/1 spikes (bf16-exact) into combined ----------------
__global__ __launch_bounds__(256) void k_lif(const float* __restrict__ proj,
                                             __hip_bfloat16* __restrict__ comb,
                                             int colOff) {
    const int b = blockIdx.x;
    const int h = threadIdx.x;
    const float* p = proj + (size_t)b * Sc * Hc + h;
    __hip_bfloat16* o = comb + (size_t)b * Sc * CH + colOff + h;
    float mem = 0.0f;
    for (int s0 = 0; s0 < Sc; s0 += 4) {
        float xs[4];
#pragma unroll
        for (int q = 0; q < 4; ++q) xs[q] = p[(size_t)(s0 + q) * Hc];
#pragma unroll
        for (int q = 0; q < 4; ++q) {
            const float reset = (mem > 1.0f) ? 1.0f : 0.0f;
            float t1 = 0.9f * mem;
            asm volatile("" : "+v"(t1));           // block FMA contraction: match np rounding
            float t2 = t1 + xs[q];
            asm volatile("" : "+v"(t2));
            mem = t2 - reset;                       // reset*THR with THR=1
            o[(size_t)(s0 + q) * CH] = __float2bfloat16((mem > 1.0f) ? 1.0f : 0.0f);
        }
    }
}

// ---------------- conv weight re-layout: w2[o][k*256+i] = cw[o][i][k] ----------------
__global__ __launch_bounds__(256) void k_w2(const float* __restrict__ cw, float* __restrict__ w2) {
    const int idx = blockIdx.x * 256 + threadIdx.x;   // < 196608
    const int o = idx / 768, rem = idx % 768;
    const int k = rem >> 8, i = rem & 255;
    w2[idx] = cw[(size_t)o * 768 + i * 3 + k];
}

// ---------------- halo-expanded conv input: ae[row][k*256+i] = plan[b, s+k-1, i] ----------------
__global__ __launch_bounds__(256) void k_aext(const float* __restrict__ plan, float* __restrict__ ae) {
    const int row = blockIdx.x;
    const int t = threadIdx.x;
    const int b = row >> 9, s = row & 511;
#pragma unroll
    for (int k = 0; k < 3; ++k) {
        const int ss = s + k - 1;
        const float v = (ss >= 0 && ss < Sc) ? plan[(size_t)(b * Sc + ss) * Hc + t] : 0.0f;
        ae[(size_t)row * 768 + k * 256 + t] = v;
    }
}

// ---------------- pack ling + plan into combined (bf16) ----------------
__global__ __launch_bounds__(256) void k_pack(const float* __restrict__ ling,
                                              const float* __restrict__ plan,
                                              __hip_bfloat16* __restrict__ comb) {
    const size_t row = blockIdx.x;
    const int t = threadIdx.x;
    comb[row * CH + 512 + t] = __float2bfloat16(ling[row * Hc + t]);
    comb[row * CH + 768 + t] = __float2bfloat16(plan[row * Hc + t]);
}

// ---------------- head_w fp32 -> bf16 ----------------
__global__ __launch_bounds__(256) void k_cvt_hw(const float* __restrict__ hw,
                                                __hip_bfloat16* __restrict__ hb) {
    const size_t i = (size_t)blockIdx.x * 256 + threadIdx.x;
    hb[i] = __float2bfloat16(hw[i]);
}

// ---------------- head GEMM: logits = combined(bf16) @ head_w(bf16)^T + head_b, fp32 out ----------------
// m97-style: 128x128 tile, BK=32, 4 waves, mfma_f32_16x16x32_bf16, global_load_lds(16B)
__global__ __launch_bounds__(256) void k_head(const __hip_bfloat16* __restrict__ Abf,
                                              const __hip_bfloat16* __restrict__ Bbf,
                                              const float* __restrict__ bias,
                                              float* __restrict__ C) {
    __shared__ __hip_bfloat16 As[128 * 32];
    __shared__ __hip_bfloat16 Bs[128 * 32];
    const int t = threadIdx.x;
    const int tm = blockIdx.x * 128, tn = blockIdx.y * 128;
    const int w = t >> 6, l = t & 63;
    const int wr = w >> 1, wc = w & 1;
    f32x4v acc[4][4];
    const f32x4v zero = {0.f, 0.f, 0.f, 0.f};
#pragma unroll
    for (int i = 0; i < 4; ++i)
#pragma unroll
        for (int j = 0; j < 4; ++j) acc[i][j] = zero;

    for (int kt = 0; kt < CH; kt += 32) {
#pragma unroll
        for (int j = 0; j < 2; ++j) {
            const int c = j * 256 + t;
            const int row = c >> 2, kc = c & 3;
            const __hip_bfloat16* ga = Abf + (size_t)(tm + row) * CH + kt + kc * 8;
            int nrow = tn + row;
            if (nrow > Vc - 1) nrow = Vc - 1;
            const __hip_bfloat16* gb = Bbf + (size_t)nrow * CH + kt + kc * 8;
            __builtin_amdgcn_global_load_lds((const __attribute__((address_space(1))) void*)ga,
                                             (__attribute__((address_space(3))) void*)(As + c * 8),
                                             16, 0, 0);
            __builtin_amdgcn_global_load_lds((const __attribute__((address_space(1))) void*)gb,
                                             (__attribute__((address_space(3))) void*)(Bs + c * 8),
                                             16, 0, 0);
        }
        __syncthreads();
        const int lr = l & 15, lk = (l >> 4) * 8;
        short8v af[4], bf[4];
#pragma unroll
        for (int m = 0; m < 4; ++m)
            af[m] = *(const short8v*)(As + (wr * 64 + m * 16 + lr) * 32 + lk);
#pragma unroll
        for (int n = 0; n < 4; ++n)
            bf[n] = *(const short8v*)(Bs + (wc * 64 + n * 16 + lr) * 32 + lk);
#pragma unroll
        for (int m = 0; m < 4; ++m)
#pragma unroll
            for (int n = 0; n < 4; ++n)
                acc[m][n] = __builtin_amdgcn_mfma_f32_16x16x32_bf16(af[m], bf[n], acc[m][n], 0, 0, 0);
        __syncthreads();
    }
    const int lr = l & 15, lq = (l >> 4) * 4;
#pragma unroll
    for (int n = 0; n < 4; ++n) {
        const int col = tn + wc * 64 + n * 16 + lr;
        if (col >= Vc) continue;
        const float bv = bias[col];
#pragma unroll
        for (int m = 0; m < 4; ++m) {
            const int rbase = tm + wr * 64 + m * 16 + lq;
#pragma unroll
            for (int j = 0; j < 4; ++j)
                C[(size_t)(rbase + j) * Vc + col] = acc[m][n][j] + bv;
        }
    }
}

// ---------------- plan mean over S ----------------
__global__ __launch_bounds__(256) void k_pmean(const float* __restrict__ plan, float* __restrict__ pm) {
    const int b = blockIdx.x;
    const int h = threadIdx.x;
    const float* p = plan + (size_t)b * Sc * Hc + h;
    float s = 0.0f;
    for (int i = 0; i < Sc; ++i) s += p[(size_t)i * Hc];
    pm[b * Hc + h] = s * (1.0f / 512.0f);
}

// ---------------- read softmax + memory read ----------------
__global__ __launch_bounds__(256) void k_memread(const float* __restrict__ pm,
                                                 const float* __restrict__ rw,
                                                 const float* __restrict__ rb,
                                                 const float* __restrict__ memm,
                                                 float* __restrict__ out) {
    const int b = blockIdx.x;
    const int t = threadIdx.x;
    __shared__ float lg[64];
    __shared__ float sm[64];
    if (t < 64) {
        float s = rb[t];
        const float* wrow = rw + (size_t)t * Hc;
        const float* p = pm + (size_t)b * Hc;
        for (int i = 0; i < Hc; ++i) s = fmaf(wrow[i], p[i], s);
        lg[t] = s;
    }
    __syncthreads();
    if (t == 0) {
        float mx = lg[0];
        for (int i = 1; i < 64; ++i) mx = fmaxf(mx, lg[i]);
        float ssum = 0.0f;
        for (int i = 0; i < 64; ++i) { const float e = expf(lg[i] - mx); sm[i] = e; ssum += e; }
        for (int i = 0; i < 64; ++i) sm[i] /= ssum;
    }
    __syncthreads();
    float s = 0.0f;
    for (int m = 0; m < 64; ++m) s = fmaf(sm[m], memm[(size_t)m * Hc + t], s);
    out[(size_t)b * Hc + t] = s;
}

extern "C" void kernel_launch(void* const* d_in, const int* in_sizes, int n_in,
                              void* d_out, int out_size, void* d_ws, size_t ws_size,
                              hipStream_t stream) {
    const int*   ids    = (const int*)  d_in[0];
    const float* embed  = (const float*)d_in[1];
    const float* pos    = (const float*)d_in[2];
    const float* qkv_w  = (const float*)d_in[3];
    const float* qkv_b  = (const float*)d_in[4];
    const float* out_w  = (const float*)d_in[5];
    const float* out_b  = (const float*)d_in[6];
    const float* ln1_g  = (const float*)d_in[7];
    const float* ln1_b  = (const float*)d_in[8];
    const float* ff1_w  = (const float*)d_in[9];
    const float* ff1_b  = (const float*)d_in[10];
    const float* ff2_w  = (const float*)d_in[11];
    const float* ff2_b  = (const float*)d_in[12];
    const float* ln2_g  = (const float*)d_in[13];
    const float* ln2_b  = (const float*)d_in[14];
    const float* log_w  = (const float*)d_in[15];
    const float* log_b  = (const float*)d_in[16];
    const float* mat_w  = (const float*)d_in[17];
    const float* mat_b  = (const float*)d_in[18];
    const float* conv_w = (const float*)d_in[19];
    const float* conv_b = (const float*)d_in[20];
    const float* read_w = (const float*)d_in[21];
    const float* read_b = (const float*)d_in[22];
    const float* memory = (const float*)d_in[23];
    const float* head_w = (const float*)d_in[24];
    const float* head_b = (const float*)d_in[25];

    char* wsb = (char*)d_ws;
    float* X   = (float*)(wsb + 0);                    //  8 MB  [8192,256]
    float* RES = (float*)(wsb + 8388608);              //  8 MB  [8192,256]
    float* QKV = (float*)(wsb + 16777216);             // 24 MB  [8192,768] (later h1, A_ext)
    float* ATT = (float*)(wsb + 41943040);             // 64 MB  [64,512,512] (later proj_log/mat)
    float* O   = (float*)(wsb + 109051904);            //  8 MB  [8192,256] (later ling)
    __hip_bfloat16* COMB = (__hip_bfloat16*)(wsb + 117440512);  // 16 MB [8192,1024]
    __hip_bfloat16* HWB  = (__hip_bfloat16*)(wsb + 134217728);  // 16 MB [8000,1024]
    float* W2  = (float*)(wsb + 150601728);            // 768 KB [256,768]
    float* PLOG = ATT;
    float* PMAT = ATT + 2097152;
    float* AEXT = QKV;
    float* PM   = RES;
    float* logits = (float*)d_out;
    float* mread  = logits + (size_t)ROWS * Vc;

    k_embed<<<dim3(ROWS), dim3(256), 0, stream>>>(ids, embed, pos, X);
    for (int l = 0; l < 2; ++l) {
        k_gemm_nt<0><<<dim3(128, 12), 256, 0, stream>>>(X, qkv_w + (size_t)l * 768 * 256,
                                                        qkv_b + l * 768, QKV, ROWS, 768, 256);
        k_scores<<<dim3(8, 8, 64), 256, 0, stream>>>(QKV, ATT);
        k_softmax<<<dim3(32768), 256, 0, stream>>>(ATT);
        k_av<<<dim3(8, 64), 256, 0, stream>>>(ATT, QKV, O);
        k_gemm_nt<0><<<dim3(128, 4), 256, 0, stream>>>(O, out_w + (size_t)l * 256 * 256,
                                                       out_b + l * 256, RES, ROWS, 256, 256);
        k_add_ln<<<dim3(ROWS), 256, 0, stream>>>(X, RES, ln1_g + l * 256, ln1_b + l * 256);
        k_gemm_nt<1><<<dim3(128, 8), 256, 0, stream>>>(X, ff1_w + (size_t)l * 512 * 256,
                                                       ff1_b + l * 512, QKV, ROWS, 512, 256);
        k_gemm_nt<0><<<dim3(128, 4), 256, 0, stream>>>(QKV, ff2_w + (size_t)l * 256 * 512,
                                                       ff2_b + l * 256, RES, ROWS, 256, 512);
        k_add_ln<<<dim3(ROWS), 256, 0, stream>>>(X, RES, ln2_g + l * 256, ln2_b + l * 256);
    }
    // plan = X
    k_gemm_nt<0><<<dim3(128, 4), 256, 0, stream>>>(X, log_w, log_b, PLOG, ROWS, 256, 256);
    k_gemm_nt<0><<<dim3(128, 4), 256, 0, stream>>>(X, mat_w, mat_b, PMAT, ROWS, 256, 256);
    k_lif<<<dim3(Bc), 256, 0, stream>>>(PLOG, COMB, 0);
    k_lif<<<dim3(Bc), 256, 0, stream>>>(PMAT, COMB, 256);
    k_w2<<<dim3(768), 256, 0, stream>>>(conv_w, W2);
    k_aext<<<dim3(ROWS), 256, 0, stream>>>(X, AEXT);
    k_gemm_nt<0><<<dim3(128, 4), 256, 0, stream>>>(AEXT, W2, conv_b, O, ROWS, 256, 768);
    k_pack<<<dim3(ROWS), 256, 0, stream>>>(O, X, COMB);
    k_cvt_hw<<<dim3(32000), 256, 0, stream>>>(head_w, HWB);
    k_head<<<dim3(64, 63), 256, 0, stream>>>(COMB, HWB, head_b, logits);
    k_pmean<<<dim3(Bc), 256, 0, stream>>>(X, PM);
    k_memread<<<dim3(Bc), 256, 0, stream>>>(PM, read_w, read_b, memory, mread);
}